// Round 1
// baseline (2417.350 us; speedup 1.0000x reference)
//
#include <hip/hip_runtime.h>
#include <stdint.h>

typedef unsigned short u16;
typedef unsigned int u32;
typedef unsigned long long u64;

#define NB 16
#define NP 4096
#define NCH 64
#define NS 1024
#define NK 32
#define H1D 128
#define H2D 256
#define KP1 96
#define LDA 104
#define LDH 136
#define OUTOFF (NB * NS * H2D) /* 4194304 */

typedef __attribute__((ext_vector_type(8))) short bfrag;
typedef __attribute__((ext_vector_type(4))) float facc4;

__device__ __forceinline__ u16 f2bf(float f) {
  u32 u = __float_as_uint(f);
  u += 0x7FFFu + ((u >> 16) & 1u);
  return (u16)(u >> 16);
}

// Exactly replicates jnp.sum((a-b)**2, axis=-1) for 3 elems: ((dx*dx+dy*dy)+dz*dz),
// no fma contraction (XLA emits plain mul/add; hipcc honors the pragma).
__device__ __forceinline__ float dist2(float ax, float ay, float az,
                                       float bx, float by, float bz) {
#pragma clang fp contract(off)
  float dx = ax - bx, dy = ay - by, dz = az - bz;
  return dx * dx + dy * dy + dz * dz;
}

// ---------------- K0: transpose + pad + bf16-convert weights ----------------
__global__ void setup_kernel(const float* __restrict__ W1, const float* __restrict__ W2,
                             u16* __restrict__ W1T, u16* __restrict__ W2T) {
  int idx = blockIdx.x * 256 + threadIdx.x;
  if (idx < H1D * KP1) {
    int n = idx / KP1, k = idx % KP1;
    W1T[idx] = f2bf(k < 67 ? W1[k * H1D + n] : 0.f);
  } else if (idx < H1D * KP1 + H2D * H1D) {
    int j = idx - H1D * KP1;
    int n = j / H1D, k = j % H1D;
    W2T[j] = f2bf(W2[k * H2D + n]);
  }
}

// ---------------- K1: farthest point sampling (1 block per cloud) ----------------
__global__ __launch_bounds__(1024) void fps_kernel(const float* __restrict__ pos,
                                                   int* __restrict__ samp,
                                                   float* __restrict__ pos_s) {
  __shared__ float plds[NP * 3];
  __shared__ float pv[2][16];
  __shared__ int pi[2][16];
  const int b = blockIdx.x;
  const int tid = threadIdx.x;
  const int lane = tid & 63, wv = tid >> 6;
  const float* pb = pos + (size_t)b * NP * 3;
  for (int k = tid; k < NP * 3; k += 1024) plds[k] = pb[k];
  __syncthreads();
  const int t4 = tid * 4;
  float px[4], py[4], pz[4], d[4];
  const float q0x = plds[0], q0y = plds[1], q0z = plds[2];
#pragma unroll
  for (int j = 0; j < 4; ++j) {
    px[j] = plds[(t4 + j) * 3 + 0];
    py[j] = plds[(t4 + j) * 3 + 1];
    pz[j] = plds[(t4 + j) * 3 + 2];
    d[j] = dist2(px[j], py[j], pz[j], q0x, q0y, q0z);
  }
  if (tid == 0) {
    samp[b * NS] = 0;
    pos_s[(size_t)b * NS * 3 + 0] = q0x;
    pos_s[(size_t)b * NS * 3 + 1] = q0y;
    pos_s[(size_t)b * NS * 3 + 2] = q0z;
  }
  for (int i = 1; i < NS; ++i) {
    // local argmax over 4 pts (ascending idx, strict > => first occurrence)
    float bv = d[0];
    int bi = t4;
    if (d[1] > bv) { bv = d[1]; bi = t4 + 1; }
    if (d[2] > bv) { bv = d[2]; bi = t4 + 2; }
    if (d[3] > bv) { bv = d[3]; bi = t4 + 3; }
#pragma unroll
    for (int m = 1; m < 64; m <<= 1) {
      float ov = __shfl_xor(bv, m);
      int oi = __shfl_xor(bi, m);
      if (ov > bv || (ov == bv && oi < bi)) { bv = ov; bi = oi; }
    }
    if (lane == 0) { pv[i & 1][wv] = bv; pi[i & 1][wv] = bi; }
    __syncthreads();
    float gv = pv[i & 1][0];
    int gi = pi[i & 1][0];
#pragma unroll
    for (int w = 1; w < 16; ++w) {
      float v = pv[i & 1][w];
      int ix = pi[i & 1][w];
      if (v > gv || (v == gv && ix < gi)) { gv = v; gi = ix; }
    }
    const float nqx = plds[gi * 3 + 0], nqy = plds[gi * 3 + 1], nqz = plds[gi * 3 + 2];
    if (tid == 0) {
      samp[b * NS + i] = gi;
      pos_s[((size_t)b * NS + i) * 3 + 0] = nqx;
      pos_s[((size_t)b * NS + i) * 3 + 1] = nqy;
      pos_s[((size_t)b * NS + i) * 3 + 2] = nqz;
    }
#pragma unroll
    for (int j = 0; j < 4; ++j)
      d[j] = fminf(d[j], dist2(px[j], py[j], pz[j], nqx, nqy, nqz));
  }
}

// ---------------- K2: ball query, exact top-K=32 by (d2, idx) key ----------------
__global__ __launch_bounds__(256) void ballq_kernel(const float* __restrict__ pos,
                                                    const int* __restrict__ samp,
                                                    int* __restrict__ nbr) {
  __shared__ u64 buf[4][512];
  const int lane = threadIdx.x & 63, wv = threadIdx.x >> 6;
  const int sg = blockIdx.x * 4 + wv;
  const int b = sg >> 10;
  const int nc = samp[sg];
  const float* pb = pos + (size_t)b * NP * 3;
  const float cx = pb[nc * 3 + 0], cy = pb[nc * 3 + 1], cz = pb[nc * 3 + 2];
  const float r2 = (float)(0.2 * 0.2);  // matches Python RADIUS*RADIUS -> f32
  int V = 0;
  for (int c = 0; c < 64; ++c) {
    const int i = c * 64 + lane;
    const float d2v = dist2(cx, cy, cz, pb[i * 3 + 0], pb[i * 3 + 1], pb[i * 3 + 2]);
    const bool valid = d2v <= r2;
    const u64 bal = __ballot(valid);
    if (valid) {
      const int rank = __popcll(bal & ((1ull << lane) - 1ull));
      const int p = V + rank;
      if (p < 512) buf[wv][p] = ((u64)__float_as_uint(d2v) << 32) | (u32)i;
    }
    V += __popcll(bal);
  }
  if (V > 512) V = 512;  // statistically unreachable (E[V]~137)
  u64 ck[8];
#pragma unroll
  for (int t = 0; t < 8; ++t) {
    const int p = t * 64 + lane;
    ck[t] = (p < V) ? buf[wv][p] : ~0ull;
  }
  u32 my = 0, pad = 0;
  for (int e = 0; e < 32; ++e) {
    u64 lm = ck[0];
#pragma unroll
    for (int t = 1; t < 8; ++t) lm = (ck[t] < lm) ? ck[t] : lm;
#pragma unroll
    for (int m = 1; m < 64; m <<= 1) {
      const u64 o = __shfl_xor(lm, m);
      lm = (o < lm) ? o : lm;
    }
    if (e == 0) pad = (u32)lm;  // centroid itself: always valid
    const u32 widx = (lm == ~0ull) ? pad : (u32)lm;
    if (lane == e) my = widx;
#pragma unroll
    for (int t = 0; t < 8; ++t)
      if (ck[t] == lm) ck[t] = ~0ull;
  }
  if (lane < 32) nbr[(size_t)sg * NK + lane] = (int)my;
}

// ---------------- K3: gather -> bf16 MFMA MLP -> maxpool ----------------
__global__ __launch_bounds__(256) void mlp_kernel(
    const float* __restrict__ x, const float* __restrict__ pos,
    const float* __restrict__ b1, const float* __restrict__ b2,
    const int* __restrict__ nbr, const u16* __restrict__ W1T,
    const u16* __restrict__ W2T, const float* __restrict__ pos_s,
    float* __restrict__ out) {
  __shared__ u16 A[128 * LDA];
  __shared__ u16 Hs[128 * LDH];
  const int ctr0 = blockIdx.x * 4;
  const int b = ctr0 >> 10;
  const int tid = threadIdx.x;
  {  // stage A tile: 128 rows x 96 cols bf16 (x | rel | zeros)
    const int row = tid >> 1, half = tid & 1;
    const int g = ctr0 + (row >> 5);
    const int n = nbr[(size_t)g * NK + (row & 31)];
    const float4* xr = (const float4*)(x + ((size_t)b * NP + n) * NCH + half * 32);
#pragma unroll
    for (int qq = 0; qq < 4; ++qq) {
      const float4 v0 = xr[2 * qq], v1 = xr[2 * qq + 1];
      uint4 wp;
      wp.x = (u32)f2bf(v0.x) | ((u32)f2bf(v0.y) << 16);
      wp.y = (u32)f2bf(v0.z) | ((u32)f2bf(v0.w) << 16);
      wp.z = (u32)f2bf(v1.x) | ((u32)f2bf(v1.y) << 16);
      wp.w = (u32)f2bf(v1.z) | ((u32)f2bf(v1.w) << 16);
      *(uint4*)&A[row * LDA + half * 32 + qq * 8] = wp;
    }
    if (half == 0) {
      const float rx = pos[((size_t)b * NP + n) * 3 + 0] - pos_s[(size_t)g * 3 + 0];
      const float ry = pos[((size_t)b * NP + n) * 3 + 1] - pos_s[(size_t)g * 3 + 1];
      const float rz = pos[((size_t)b * NP + n) * 3 + 2] - pos_s[(size_t)g * 3 + 2];
      uint4 wr;
      wr.x = (u32)f2bf(rx) | ((u32)f2bf(ry) << 16);
      wr.y = (u32)f2bf(rz);
      wr.z = 0; wr.w = 0;
      uint4 wz;
      wz.x = wz.y = wz.z = wz.w = 0;
      *(uint4*)&A[row * LDA + 64] = wr;
      *(uint4*)&A[row * LDA + 72] = wz;
      *(uint4*)&A[row * LDA + 80] = wz;
      *(uint4*)&A[row * LDA + 88] = wz;
    }
  }
  __syncthreads();
  const int lane = tid & 63, w = tid >> 6;
  const int r16 = lane & 15, g4 = lane >> 4;
  {  // layer 1: [128x96] @ [96x128] -> relu -> Hs bf16
    bfrag af[2][3];
#pragma unroll
    for (int mg2 = 0; mg2 < 2; ++mg2)
#pragma unroll
      for (int ks = 0; ks < 3; ++ks)
        af[mg2][ks] = *(const bfrag*)&A[((2 * w + mg2) * 16 + r16) * LDA + ks * 32 + g4 * 8];
#pragma unroll
    for (int ng = 0; ng < 8; ++ng) {
      const bfrag bw0 = *(const bfrag*)&W1T[(ng * 16 + r16) * KP1 + 0 + g4 * 8];
      const bfrag bw1 = *(const bfrag*)&W1T[(ng * 16 + r16) * KP1 + 32 + g4 * 8];
      const bfrag bw2 = *(const bfrag*)&W1T[(ng * 16 + r16) * KP1 + 64 + g4 * 8];
      facc4 a0 = {0.f, 0.f, 0.f, 0.f}, a1 = {0.f, 0.f, 0.f, 0.f};
      a0 = __builtin_amdgcn_mfma_f32_16x16x32_bf16(af[0][0], bw0, a0, 0, 0, 0);
      a0 = __builtin_amdgcn_mfma_f32_16x16x32_bf16(af[0][1], bw1, a0, 0, 0, 0);
      a0 = __builtin_amdgcn_mfma_f32_16x16x32_bf16(af[0][2], bw2, a0, 0, 0, 0);
      a1 = __builtin_amdgcn_mfma_f32_16x16x32_bf16(af[1][0], bw0, a1, 0, 0, 0);
      a1 = __builtin_amdgcn_mfma_f32_16x16x32_bf16(af[1][1], bw1, a1, 0, 0, 0);
      a1 = __builtin_amdgcn_mfma_f32_16x16x32_bf16(af[1][2], bw2, a1, 0, 0, 0);
      const float bias = b1[ng * 16 + r16];
#pragma unroll
      for (int r = 0; r < 4; ++r) {
        Hs[((2 * w + 0) * 16 + g4 * 4 + r) * LDH + ng * 16 + r16] = f2bf(fmaxf(a0[r] + bias, 0.f));
        Hs[((2 * w + 1) * 16 + g4 * 4 + r) * LDH + ng * 16 + r16] = f2bf(fmaxf(a1[r] + bias, 0.f));
      }
    }
  }
  __syncthreads();
  {  // layer 2 + maxpool: wave w owns centroid w (rows 32w..32w+31)
    bfrag hf[2][4];
#pragma unroll
    for (int mg2 = 0; mg2 < 2; ++mg2)
#pragma unroll
      for (int ks = 0; ks < 4; ++ks)
        hf[mg2][ks] = *(const bfrag*)&Hs[((2 * w + mg2) * 16 + r16) * LDH + ks * 32 + g4 * 8];
    const int gout = ctr0 + w;
#pragma unroll
    for (int ng = 0; ng < 16; ++ng) {
      facc4 a0 = {0.f, 0.f, 0.f, 0.f}, a1 = {0.f, 0.f, 0.f, 0.f};
#pragma unroll
      for (int ks = 0; ks < 4; ++ks) {
        const bfrag bw = *(const bfrag*)&W2T[(ng * 16 + r16) * H1D + ks * 32 + g4 * 8];
        a0 = __builtin_amdgcn_mfma_f32_16x16x32_bf16(hf[0][ks], bw, a0, 0, 0, 0);
        a1 = __builtin_amdgcn_mfma_f32_16x16x32_bf16(hf[1][ks], bw, a1, 0, 0, 0);
      }
      // max over the centroid's 32 rows; bias+relu commute with max
      float m0 = fmaxf(fmaxf(a0[0], a0[1]), fmaxf(a0[2], a0[3]));
      float m1 = fmaxf(fmaxf(a1[0], a1[1]), fmaxf(a1[2], a1[3]));
      float mm = fmaxf(m0, m1);
      mm = fmaxf(mm, __shfl_xor(mm, 16));
      mm = fmaxf(mm, __shfl_xor(mm, 32));
      const float ov = fmaxf(mm + b2[ng * 16 + r16], 0.f);
      if (lane < 16) out[(size_t)gout * H2D + ng * 16 + lane] = ov;
    }
  }
}

extern "C" void kernel_launch(void* const* d_in, const int* in_sizes, int n_in,
                              void* d_out, int out_size, void* d_ws, size_t ws_size,
                              hipStream_t stream) {
  const float* x = (const float*)d_in[0];
  const float* pos = (const float*)d_in[1];
  const float* W1 = (const float*)d_in[2];
  const float* b1 = (const float*)d_in[3];
  const float* W2 = (const float*)d_in[4];
  const float* b2 = (const float*)d_in[5];
  float* out = (float*)d_out;
  char* ws = (char*)d_ws;
  u16* W1T = (u16*)(ws + 0);           // 24576 B
  u16* W2T = (u16*)(ws + 24576);       // 65536 B
  int* samp = (int*)(ws + 90112);      // 65536 B
  int* nbr = (int*)(ws + 155648);      // 2 MiB
  float* pos_s = out + OUTOFF;

  setup_kernel<<<dim3(176), dim3(256), 0, stream>>>(W1, W2, W1T, W2T);
  fps_kernel<<<dim3(NB), dim3(1024), 0, stream>>>(pos, samp, pos_s);
  ballq_kernel<<<dim3(NB * NS / 4), dim3(256), 0, stream>>>(pos, samp, nbr);
  mlp_kernel<<<dim3(NB * NS / 4), dim3(256), 0, stream>>>(x, pos, b1, b2, nbr, W1T, W2T,
                                                          pos_s, out);
}

// Round 2
// 1108.483 us; speedup vs baseline: 2.1808x; 2.1808x over previous
//
#include <hip/hip_runtime.h>
#include <stdint.h>

typedef unsigned short u16;
typedef unsigned int u32;
typedef unsigned long long u64;

#define NB 16
#define NP 4096
#define NCH 64
#define NS 1024
#define NK 32
#define H1D 128
#define H2D 256
#define KP1 96
#define LDA 104
#define LDH 136
#define OUTOFF (NB * NS * H2D) /* 4194304 */

typedef __attribute__((ext_vector_type(8))) short bfrag;
typedef __attribute__((ext_vector_type(4))) float facc4;

__device__ __forceinline__ u16 f2bf(float f) {
  u32 u = __float_as_uint(f);
  u += 0x7FFFu + ((u >> 16) & 1u);
  return (u16)(u >> 16);
}

// Exactly replicates jnp.sum((a-b)**2, axis=-1) for 3 elems: ((dx*dx+dy*dy)+dz*dz),
// no fma contraction (XLA emits plain mul/add; hipcc honors the pragma).
__device__ __forceinline__ float dist2(float ax, float ay, float az,
                                       float bx, float by, float bz) {
#pragma clang fp contract(off)
  float dx = ax - bx, dy = ay - by, dz = az - bz;
  return dx * dx + dy * dy + dz * dz;
}

// ---------------- K0: transpose + pad + bf16-convert weights ----------------
__global__ void setup_kernel(const float* __restrict__ W1, const float* __restrict__ W2,
                             u16* __restrict__ W1T, u16* __restrict__ W2T) {
  int idx = blockIdx.x * 256 + threadIdx.x;
  if (idx < H1D * KP1) {
    int n = idx / KP1, k = idx % KP1;
    W1T[idx] = f2bf(k < 67 ? W1[k * H1D + n] : 0.f);
  } else if (idx < H1D * KP1 + H2D * H1D) {
    int j = idx - H1D * KP1;
    int n = j / H1D, k = j % H1D;
    W2T[j] = f2bf(W2[k * H2D + n]);
  }
}

// ---------------- K1: farthest point sampling (1 block per cloud) ----------------
// 256 threads = 4 waves (1/SIMD); 16 pts/thread in registers; u64 (d2,~idx) keys.
__global__ __launch_bounds__(256) void fps_kernel(const float* __restrict__ pos,
                                                  int* __restrict__ samp,
                                                  float* __restrict__ pos_s) {
  __shared__ float4 plds[NP];      // 64 KiB: pos as float4 for b128 broadcast
  __shared__ u64 wkey[2][4];
  const int b = blockIdx.x;
  const int tid = threadIdx.x;
  const int lane = tid & 63, wv = tid >> 6;
  const float* pb = pos + (size_t)b * NP * 3;
  for (int k = tid; k < NP; k += 256)
    plds[k] = make_float4(pb[k * 3 + 0], pb[k * 3 + 1], pb[k * 3 + 2], 0.f);
  __syncthreads();

  float px[16], py[16], pz[16], d[16];
  const float4 q0 = plds[0];
  const u32 encb = 4095u - (u32)tid;  // key low word: 4095 - idx (ties -> smaller idx)
  u64 bk = 0;
#pragma unroll
  for (int j = 0; j < 16; ++j) {
    const float4 p = plds[j * 256 + tid];
    px[j] = p.x; py[j] = p.y; pz[j] = p.z;
    d[j] = dist2(p.x, p.y, p.z, q0.x, q0.y, q0.z);
    const u64 key = ((u64)__float_as_uint(d[j]) << 32) | (u64)(encb - j * 256u);
    bk = key > bk ? key : bk;
  }
  if (tid == 0) {
    samp[b * NS] = 0;
    pos_s[(size_t)b * NS * 3 + 0] = q0.x;
    pos_s[(size_t)b * NS * 3 + 1] = q0.y;
    pos_s[(size_t)b * NS * 3 + 2] = q0.z;
  }

  for (int i = 1; i < NS; ++i) {
    // wave-local butterfly max over u64 keys
#pragma unroll
    for (int m = 1; m < 64; m <<= 1) {
      const u64 o = __shfl_xor(bk, m);
      bk = o > bk ? o : bk;
    }
    if (lane == 0) wkey[i & 1][wv] = bk;
    __syncthreads();
    // cross-wave: all threads redundantly reduce the 4 partials
    u64 g = wkey[i & 1][0];
    u64 g1 = wkey[i & 1][1];
    u64 g2 = wkey[i & 1][2];
    u64 g3 = wkey[i & 1][3];
    g = g1 > g ? g1 : g;
    g = g2 > g ? g2 : g;
    g = g3 > g ? g3 : g;
    const int gi = 4095 - (int)(u32)g;
    const float4 q = plds[gi];  // broadcast read
    if (tid == 0) {
      samp[b * NS + i] = gi;
      pos_s[((size_t)b * NS + i) * 3 + 0] = q.x;
      pos_s[((size_t)b * NS + i) * 3 + 1] = q.y;
      pos_s[((size_t)b * NS + i) * 3 + 2] = q.z;
    }
    // fused d-update + next local argmax
    bk = 0;
#pragma unroll
    for (int j = 0; j < 16; ++j) {
      d[j] = fminf(d[j], dist2(px[j], py[j], pz[j], q.x, q.y, q.z));
      const u64 key = ((u64)__float_as_uint(d[j]) << 32) | (u64)(encb - j * 256u);
      bk = key > bk ? key : bk;
    }
  }
}

// ---------------- K2: ball query, exact top-K=32 by (d2, idx) key ----------------
__global__ __launch_bounds__(256) void ballq_kernel(const float* __restrict__ pos,
                                                    const int* __restrict__ samp,
                                                    int* __restrict__ nbr) {
  __shared__ u64 buf[4][512];
  const int lane = threadIdx.x & 63, wv = threadIdx.x >> 6;
  const int sg = blockIdx.x * 4 + wv;
  const int b = sg >> 10;
  const int nc = samp[sg];
  const float* pb = pos + (size_t)b * NP * 3;
  const float cx = pb[nc * 3 + 0], cy = pb[nc * 3 + 1], cz = pb[nc * 3 + 2];
  const float r2 = (float)(0.2 * 0.2);  // matches Python RADIUS*RADIUS -> f32
  int V = 0;
  for (int c = 0; c < 64; ++c) {
    const int i = c * 64 + lane;
    const float d2v = dist2(cx, cy, cz, pb[i * 3 + 0], pb[i * 3 + 1], pb[i * 3 + 2]);
    const bool valid = d2v <= r2;
    const u64 bal = __ballot(valid);
    if (valid) {
      const int rank = __popcll(bal & ((1ull << lane) - 1ull));
      const int p = V + rank;
      if (p < 512) buf[wv][p] = ((u64)__float_as_uint(d2v) << 32) | (u32)i;
    }
    V += __popcll(bal);
  }
  if (V > 512) V = 512;  // statistically unreachable (E[V]~137)
  u64 ck[8];
#pragma unroll
  for (int t = 0; t < 8; ++t) {
    const int p = t * 64 + lane;
    ck[t] = (p < V) ? buf[wv][p] : ~0ull;
  }
  u32 my = 0, pad = 0;
  for (int e = 0; e < 32; ++e) {
    u64 lm = ck[0];
#pragma unroll
    for (int t = 1; t < 8; ++t) lm = (ck[t] < lm) ? ck[t] : lm;
#pragma unroll
    for (int m = 1; m < 64; m <<= 1) {
      const u64 o = __shfl_xor(lm, m);
      lm = (o < lm) ? o : lm;
    }
    if (e == 0) pad = (u32)lm;  // centroid itself: always valid
    const u32 widx = (lm == ~0ull) ? pad : (u32)lm;
    if (lane == e) my = widx;
#pragma unroll
    for (int t = 0; t < 8; ++t)
      if (ck[t] == lm) ck[t] = ~0ull;
  }
  if (lane < 32) nbr[(size_t)sg * NK + lane] = (int)my;
}

// ---------------- K3: gather -> bf16 MFMA MLP -> maxpool ----------------
__global__ __launch_bounds__(256) void mlp_kernel(
    const float* __restrict__ x, const float* __restrict__ pos,
    const float* __restrict__ b1, const float* __restrict__ b2,
    const int* __restrict__ nbr, const u16* __restrict__ W1T,
    const u16* __restrict__ W2T, const float* __restrict__ pos_s,
    float* __restrict__ out) {
  __shared__ u16 A[128 * LDA];
  __shared__ u16 Hs[128 * LDH];
  const int ctr0 = blockIdx.x * 4;
  const int b = ctr0 >> 10;
  const int tid = threadIdx.x;
  {  // stage A tile: 128 rows x 96 cols bf16 (x | rel | zeros)
    const int row = tid >> 1, half = tid & 1;
    const int g = ctr0 + (row >> 5);
    const int n = nbr[(size_t)g * NK + (row & 31)];
    const float4* xr = (const float4*)(x + ((size_t)b * NP + n) * NCH + half * 32);
#pragma unroll
    for (int qq = 0; qq < 4; ++qq) {
      const float4 v0 = xr[2 * qq], v1 = xr[2 * qq + 1];
      uint4 wp;
      wp.x = (u32)f2bf(v0.x) | ((u32)f2bf(v0.y) << 16);
      wp.y = (u32)f2bf(v0.z) | ((u32)f2bf(v0.w) << 16);
      wp.z = (u32)f2bf(v1.x) | ((u32)f2bf(v1.y) << 16);
      wp.w = (u32)f2bf(v1.z) | ((u32)f2bf(v1.w) << 16);
      *(uint4*)&A[row * LDA + half * 32 + qq * 8] = wp;
    }
    if (half == 0) {
      const float rx = pos[((size_t)b * NP + n) * 3 + 0] - pos_s[(size_t)g * 3 + 0];
      const float ry = pos[((size_t)b * NP + n) * 3 + 1] - pos_s[(size_t)g * 3 + 1];
      const float rz = pos[((size_t)b * NP + n) * 3 + 2] - pos_s[(size_t)g * 3 + 2];
      uint4 wr;
      wr.x = (u32)f2bf(rx) | ((u32)f2bf(ry) << 16);
      wr.y = (u32)f2bf(rz);
      wr.z = 0; wr.w = 0;
      uint4 wz;
      wz.x = wz.y = wz.z = wz.w = 0;
      *(uint4*)&A[row * LDA + 64] = wr;
      *(uint4*)&A[row * LDA + 72] = wz;
      *(uint4*)&A[row * LDA + 80] = wz;
      *(uint4*)&A[row * LDA + 88] = wz;
    }
  }
  __syncthreads();
  const int lane = tid & 63, w = tid >> 6;
  const int r16 = lane & 15, g4 = lane >> 4;
  {  // layer 1: [128x96] @ [96x128] -> relu -> Hs bf16
    bfrag af[2][3];
#pragma unroll
    for (int mg2 = 0; mg2 < 2; ++mg2)
#pragma unroll
      for (int ks = 0; ks < 3; ++ks)
        af[mg2][ks] = *(const bfrag*)&A[((2 * w + mg2) * 16 + r16) * LDA + ks * 32 + g4 * 8];
#pragma unroll
    for (int ng = 0; ng < 8; ++ng) {
      const bfrag bw0 = *(const bfrag*)&W1T[(ng * 16 + r16) * KP1 + 0 + g4 * 8];
      const bfrag bw1 = *(const bfrag*)&W1T[(ng * 16 + r16) * KP1 + 32 + g4 * 8];
      const bfrag bw2 = *(const bfrag*)&W1T[(ng * 16 + r16) * KP1 + 64 + g4 * 8];
      facc4 a0 = {0.f, 0.f, 0.f, 0.f}, a1 = {0.f, 0.f, 0.f, 0.f};
      a0 = __builtin_amdgcn_mfma_f32_16x16x32_bf16(af[0][0], bw0, a0, 0, 0, 0);
      a0 = __builtin_amdgcn_mfma_f32_16x16x32_bf16(af[0][1], bw1, a0, 0, 0, 0);
      a0 = __builtin_amdgcn_mfma_f32_16x16x32_bf16(af[0][2], bw2, a0, 0, 0, 0);
      a1 = __builtin_amdgcn_mfma_f32_16x16x32_bf16(af[1][0], bw0, a1, 0, 0, 0);
      a1 = __builtin_amdgcn_mfma_f32_16x16x32_bf16(af[1][1], bw1, a1, 0, 0, 0);
      a1 = __builtin_amdgcn_mfma_f32_16x16x32_bf16(af[1][2], bw2, a1, 0, 0, 0);
      const float bias = b1[ng * 16 + r16];
#pragma unroll
      for (int r = 0; r < 4; ++r) {
        Hs[((2 * w + 0) * 16 + g4 * 4 + r) * LDH + ng * 16 + r16] = f2bf(fmaxf(a0[r] + bias, 0.f));
        Hs[((2 * w + 1) * 16 + g4 * 4 + r) * LDH + ng * 16 + r16] = f2bf(fmaxf(a1[r] + bias, 0.f));
      }
    }
  }
  __syncthreads();
  {  // layer 2 + maxpool: wave w owns centroid w (rows 32w..32w+31)
    bfrag hf[2][4];
#pragma unroll
    for (int mg2 = 0; mg2 < 2; ++mg2)
#pragma unroll
      for (int ks = 0; ks < 4; ++ks)
        hf[mg2][ks] = *(const bfrag*)&Hs[((2 * w + mg2) * 16 + r16) * LDH + ks * 32 + g4 * 8];
    const int gout = ctr0 + w;
#pragma unroll
    for (int ng = 0; ng < 16; ++ng) {
      facc4 a0 = {0.f, 0.f, 0.f, 0.f}, a1 = {0.f, 0.f, 0.f, 0.f};
#pragma unroll
      for (int ks = 0; ks < 4; ++ks) {
        const bfrag bw = *(const bfrag*)&W2T[(ng * 16 + r16) * H1D + ks * 32 + g4 * 8];
        a0 = __builtin_amdgcn_mfma_f32_16x16x32_bf16(hf[0][ks], bw, a0, 0, 0, 0);
        a1 = __builtin_amdgcn_mfma_f32_16x16x32_bf16(hf[1][ks], bw, a1, 0, 0, 0);
      }
      // max over the centroid's 32 rows; bias+relu commute with max
      float m0 = fmaxf(fmaxf(a0[0], a0[1]), fmaxf(a0[2], a0[3]));
      float m1 = fmaxf(fmaxf(a1[0], a1[1]), fmaxf(a1[2], a1[3]));
      float mm = fmaxf(m0, m1);
      mm = fmaxf(mm, __shfl_xor(mm, 16));
      mm = fmaxf(mm, __shfl_xor(mm, 32));
      const float ov = fmaxf(mm + b2[ng * 16 + r16], 0.f);
      if (lane < 16) out[(size_t)gout * H2D + ng * 16 + lane] = ov;
    }
  }
}

extern "C" void kernel_launch(void* const* d_in, const int* in_sizes, int n_in,
                              void* d_out, int out_size, void* d_ws, size_t ws_size,
                              hipStream_t stream) {
  const float* x = (const float*)d_in[0];
  const float* pos = (const float*)d_in[1];
  const float* W1 = (const float*)d_in[2];
  const float* b1 = (const float*)d_in[3];
  const float* W2 = (const float*)d_in[4];
  const float* b2 = (const float*)d_in[5];
  float* out = (float*)d_out;
  char* ws = (char*)d_ws;
  u16* W1T = (u16*)(ws + 0);           // 24576 B
  u16* W2T = (u16*)(ws + 24576);       // 65536 B
  int* samp = (int*)(ws + 90112);      // 65536 B
  int* nbr = (int*)(ws + 155648);      // 2 MiB
  float* pos_s = out + OUTOFF;

  setup_kernel<<<dim3(176), dim3(256), 0, stream>>>(W1, W2, W1T, W2T);
  fps_kernel<<<dim3(NB), dim3(256), 0, stream>>>(pos, samp, pos_s);
  ballq_kernel<<<dim3(NB * NS / 4), dim3(256), 0, stream>>>(pos, samp, nbr);
  mlp_kernel<<<dim3(NB * NS / 4), dim3(256), 0, stream>>>(x, pos, b1, b2, nbr, W1T, W2T,
                                                          pos_s, out);
}

// Round 3
// 1000.345 us; speedup vs baseline: 2.4165x; 1.1081x over previous
//
#include <hip/hip_runtime.h>
#include <stdint.h>

typedef unsigned short u16;
typedef unsigned int u32;
typedef unsigned long long u64;

#define NB 16
#define NP 4096
#define NCH 64
#define NS 1024
#define NK 32
#define H1D 128
#define H2D 256
#define KP1 96
#define LDA 104
#define LDH 136
#define OUTOFF (NB * NS * H2D) /* 4194304 */

typedef __attribute__((ext_vector_type(8))) short bfrag;
typedef __attribute__((ext_vector_type(4))) float facc4;

__device__ __forceinline__ u16 f2bf(float f) {
  u32 u = __float_as_uint(f);
  u += 0x7FFFu + ((u >> 16) & 1u);
  return (u16)(u >> 16);
}

// Exactly replicates jnp.sum((a-b)**2, axis=-1) for 3 elems: ((dx*dx+dy*dy)+dz*dz),
// no fma contraction (XLA emits plain mul/add; hipcc honors the pragma).
__device__ __forceinline__ float dist2(float ax, float ay, float az,
                                       float bx, float by, float bz) {
#pragma clang fp contract(off)
  float dx = ax - bx, dy = ay - by, dz = az - bz;
  return dx * dx + dy * dy + dz * dz;
}

// Full-wave (64-lane) max via DPP on the VALU pipe; result returned uniform.
__device__ __forceinline__ float wave_max_f32(float v) {
  const int NI = (int)0xFF800000u;  // -inf bits = identity for max
  v = fmaxf(v, __int_as_float(__builtin_amdgcn_update_dpp(NI, __float_as_int(v), 0x111, 0xf, 0xf, false)));
  v = fmaxf(v, __int_as_float(__builtin_amdgcn_update_dpp(NI, __float_as_int(v), 0x112, 0xf, 0xf, false)));
  v = fmaxf(v, __int_as_float(__builtin_amdgcn_update_dpp(NI, __float_as_int(v), 0x114, 0xf, 0xf, false)));
  v = fmaxf(v, __int_as_float(__builtin_amdgcn_update_dpp(NI, __float_as_int(v), 0x118, 0xf, 0xf, false)));
  v = fmaxf(v, __int_as_float(__builtin_amdgcn_update_dpp(NI, __float_as_int(v), 0x142, 0xa, 0xf, false)));
  v = fmaxf(v, __int_as_float(__builtin_amdgcn_update_dpp(NI, __float_as_int(v), 0x143, 0xc, 0xf, false)));
  return __int_as_float(__builtin_amdgcn_readlane(__float_as_int(v), 63));
}

// Full-wave (64-lane) min of u32 via DPP; result returned uniform.
__device__ __forceinline__ u32 wave_min_u32(u32 v) {
  u32 t;
  t = (u32)__builtin_amdgcn_update_dpp(-1, (int)v, 0x111, 0xf, 0xf, false); v = t < v ? t : v;
  t = (u32)__builtin_amdgcn_update_dpp(-1, (int)v, 0x112, 0xf, 0xf, false); v = t < v ? t : v;
  t = (u32)__builtin_amdgcn_update_dpp(-1, (int)v, 0x114, 0xf, 0xf, false); v = t < v ? t : v;
  t = (u32)__builtin_amdgcn_update_dpp(-1, (int)v, 0x118, 0xf, 0xf, false); v = t < v ? t : v;
  t = (u32)__builtin_amdgcn_update_dpp(-1, (int)v, 0x142, 0xa, 0xf, false); v = t < v ? t : v;
  t = (u32)__builtin_amdgcn_update_dpp(-1, (int)v, 0x143, 0xc, 0xf, false); v = t < v ? t : v;
  return (u32)__builtin_amdgcn_readlane((int)v, 63);
}

// ---------------- K0: transpose + pad + bf16-convert weights ----------------
__global__ void setup_kernel(const float* __restrict__ W1, const float* __restrict__ W2,
                             u16* __restrict__ W1T, u16* __restrict__ W2T) {
  int idx = blockIdx.x * 256 + threadIdx.x;
  if (idx < H1D * KP1) {
    int n = idx / KP1, k = idx % KP1;
    W1T[idx] = f2bf(k < 67 ? W1[k * H1D + n] : 0.f);
  } else if (idx < H1D * KP1 + H2D * H1D) {
    int j = idx - H1D * KP1;
    int n = j / H1D, k = j % H1D;
    W2T[j] = f2bf(W2[k * H2D + n]);
  }
}

// ---------------- K1: farthest point sampling (1 block per cloud) ----------------
// 256 threads = 4 waves (1/SIMD); 16 pts/thread in registers; DPP argmax reduce.
__global__ __launch_bounds__(256) void fps_kernel(const float* __restrict__ pos,
                                                  int* __restrict__ samp,
                                                  float* __restrict__ pos_s) {
  __shared__ float4 plds[NP];      // 64 KiB: pos as float4 for b128 broadcast
  __shared__ __align__(16) u64 wkey[2][4];
  const int b = blockIdx.x;
  const int tid = threadIdx.x;
  const int lane = tid & 63, wv = tid >> 6;
  const float* pb = pos + (size_t)b * NP * 3;
  for (int k = tid; k < NP; k += 256)
    plds[k] = make_float4(pb[k * 3 + 0], pb[k * 3 + 1], pb[k * 3 + 2], 0.f);
  __syncthreads();

  float px[16], py[16], pz[16], d[16];
  const float4 q0 = plds[0];
  float bv = -1.f;
  int bj = 0;
#pragma unroll
  for (int j = 0; j < 16; ++j) {
    const float4 p = plds[j * 256 + tid];
    px[j] = p.x; py[j] = p.y; pz[j] = p.z;
    d[j] = dist2(p.x, p.y, p.z, q0.x, q0.y, q0.z);
    const bool c = d[j] > bv;  // ascending j, strict > => first occurrence
    bv = c ? d[j] : bv;
    bj = c ? j : bj;
  }
  if (tid == 0) {
    samp[b * NS] = 0;
    pos_s[(size_t)b * NS * 3 + 0] = q0.x;
    pos_s[(size_t)b * NS * 3 + 1] = q0.y;
    pos_s[(size_t)b * NS * 3 + 2] = q0.z;
  }

  for (int i = 1; i < NS; ++i) {
    // phase 1: wave max value (VALU DPP, no LDS)
    const float wmax = wave_max_f32(bv);
    // phase 2: exact first-occurrence index among tied lanes
    const u32 cand = (bv == wmax) ? (u32)(bj * 256 + tid) : 0xFFFFFFFFu;
    const u32 widx = wave_min_u32(cand);
    if (lane == 0)
      wkey[i & 1][wv] = ((u64)__float_as_uint(wmax) << 32) | (u64)(4095u - widx);
    __syncthreads();
    // cross-wave: 2 overlapped 16B LDS reads + 3 u64 compares, all threads
    const ulonglong2 k01 = *(const ulonglong2*)&wkey[i & 1][0];
    const ulonglong2 k23 = *(const ulonglong2*)&wkey[i & 1][2];
    u64 g = k01.x;
    g = k01.y > g ? k01.y : g;
    g = k23.x > g ? k23.x : g;
    g = k23.y > g ? k23.y : g;
    const int gi = __builtin_amdgcn_readfirstlane(4095 - (int)((u32)g & 0xFFFu));
    const float4 q = plds[gi];  // uniform address -> broadcast read
    if (tid == 0) {
      samp[b * NS + i] = gi;
      pos_s[((size_t)b * NS + i) * 3 + 0] = q.x;
      pos_s[((size_t)b * NS + i) * 3 + 1] = q.y;
      pos_s[((size_t)b * NS + i) * 3 + 2] = q.z;
    }
    // fused d-update + next local argmax
    bv = -1.f; bj = 0;
#pragma unroll
    for (int j = 0; j < 16; ++j) {
      d[j] = fminf(d[j], dist2(px[j], py[j], pz[j], q.x, q.y, q.z));
      const bool c = d[j] > bv;
      bv = c ? d[j] : bv;
      bj = c ? j : bj;
    }
  }
}

// ---------------- K2: ball query, exact top-K=32 by (d2, idx) key ----------------
__global__ __launch_bounds__(256) void ballq_kernel(const float* __restrict__ pos,
                                                    const int* __restrict__ samp,
                                                    int* __restrict__ nbr) {
  __shared__ u64 buf[4][512];
  const int lane = threadIdx.x & 63, wv = threadIdx.x >> 6;
  const int sg = blockIdx.x * 4 + wv;
  const int b = sg >> 10;
  const int nc = samp[sg];
  const float* pb = pos + (size_t)b * NP * 3;
  const float cx = pb[nc * 3 + 0], cy = pb[nc * 3 + 1], cz = pb[nc * 3 + 2];
  const float r2 = (float)(0.2 * 0.2);  // matches Python RADIUS*RADIUS -> f32
  int V = 0;
  for (int c = 0; c < 64; ++c) {
    const int i = c * 64 + lane;
    const float d2v = dist2(cx, cy, cz, pb[i * 3 + 0], pb[i * 3 + 1], pb[i * 3 + 2]);
    const bool valid = d2v <= r2;
    const u64 bal = __ballot(valid);
    if (valid) {
      const int rank = __popcll(bal & ((1ull << lane) - 1ull));
      const int p = V + rank;
      if (p < 512) buf[wv][p] = ((u64)__float_as_uint(d2v) << 32) | (u32)i;
    }
    V += __popcll(bal);
  }
  if (V > 512) V = 512;  // statistically unreachable (E[V]~137)
  u64 ck[8];
#pragma unroll
  for (int t = 0; t < 8; ++t) {
    const int p = t * 64 + lane;
    ck[t] = (p < V) ? buf[wv][p] : ~0ull;
  }
  u32 my = 0, pad = 0;
  for (int e = 0; e < 32; ++e) {
    u64 lm = ck[0];
#pragma unroll
    for (int t = 1; t < 8; ++t) lm = (ck[t] < lm) ? ck[t] : lm;
#pragma unroll
    for (int m = 1; m < 64; m <<= 1) {
      const u64 o = __shfl_xor(lm, m);
      lm = (o < lm) ? o : lm;
    }
    if (e == 0) pad = (u32)lm;  // centroid itself: always valid
    const u32 widx = (lm == ~0ull) ? pad : (u32)lm;
    if (lane == e) my = widx;
#pragma unroll
    for (int t = 0; t < 8; ++t)
      if (ck[t] == lm) ck[t] = ~0ull;
  }
  if (lane < 32) nbr[(size_t)sg * NK + lane] = (int)my;
}

// ---------------- K3: gather -> bf16 MFMA MLP -> maxpool ----------------
__global__ __launch_bounds__(256) void mlp_kernel(
    const float* __restrict__ x, const float* __restrict__ pos,
    const float* __restrict__ b1, const float* __restrict__ b2,
    const int* __restrict__ nbr, const u16* __restrict__ W1T,
    const u16* __restrict__ W2T, const float* __restrict__ pos_s,
    float* __restrict__ out) {
  __shared__ u16 A[128 * LDA];
  __shared__ u16 Hs[128 * LDH];
  const int ctr0 = blockIdx.x * 4;
  const int b = ctr0 >> 10;
  const int tid = threadIdx.x;
  {  // stage A tile: 128 rows x 96 cols bf16 (x | rel | zeros)
    const int row = tid >> 1, half = tid & 1;
    const int g = ctr0 + (row >> 5);
    const int n = nbr[(size_t)g * NK + (row & 31)];
    const float4* xr = (const float4*)(x + ((size_t)b * NP + n) * NCH + half * 32);
#pragma unroll
    for (int qq = 0; qq < 4; ++qq) {
      const float4 v0 = xr[2 * qq], v1 = xr[2 * qq + 1];
      uint4 wp;
      wp.x = (u32)f2bf(v0.x) | ((u32)f2bf(v0.y) << 16);
      wp.y = (u32)f2bf(v0.z) | ((u32)f2bf(v0.w) << 16);
      wp.z = (u32)f2bf(v1.x) | ((u32)f2bf(v1.y) << 16);
      wp.w = (u32)f2bf(v1.z) | ((u32)f2bf(v1.w) << 16);
      *(uint4*)&A[row * LDA + half * 32 + qq * 8] = wp;
    }
    if (half == 0) {
      const float rx = pos[((size_t)b * NP + n) * 3 + 0] - pos_s[(size_t)g * 3 + 0];
      const float ry = pos[((size_t)b * NP + n) * 3 + 1] - pos_s[(size_t)g * 3 + 1];
      const float rz = pos[((size_t)b * NP + n) * 3 + 2] - pos_s[(size_t)g * 3 + 2];
      uint4 wr;
      wr.x = (u32)f2bf(rx) | ((u32)f2bf(ry) << 16);
      wr.y = (u32)f2bf(rz);
      wr.z = 0; wr.w = 0;
      uint4 wz;
      wz.x = wz.y = wz.z = wz.w = 0;
      *(uint4*)&A[row * LDA + 64] = wr;
      *(uint4*)&A[row * LDA + 72] = wz;
      *(uint4*)&A[row * LDA + 80] = wz;
      *(uint4*)&A[row * LDA + 88] = wz;
    }
  }
  __syncthreads();
  const int lane = tid & 63, w = tid >> 6;
  const int r16 = lane & 15, g4 = lane >> 4;
  {  // layer 1: [128x96] @ [96x128] -> relu -> Hs bf16
    bfrag af[2][3];
#pragma unroll
    for (int mg2 = 0; mg2 < 2; ++mg2)
#pragma unroll
      for (int ks = 0; ks < 3; ++ks)
        af[mg2][ks] = *(const bfrag*)&A[((2 * w + mg2) * 16 + r16) * LDA + ks * 32 + g4 * 8];
#pragma unroll
    for (int ng = 0; ng < 8; ++ng) {
      const bfrag bw0 = *(const bfrag*)&W1T[(ng * 16 + r16) * KP1 + 0 + g4 * 8];
      const bfrag bw1 = *(const bfrag*)&W1T[(ng * 16 + r16) * KP1 + 32 + g4 * 8];
      const bfrag bw2 = *(const bfrag*)&W1T[(ng * 16 + r16) * KP1 + 64 + g4 * 8];
      facc4 a0 = {0.f, 0.f, 0.f, 0.f}, a1 = {0.f, 0.f, 0.f, 0.f};
      a0 = __builtin_amdgcn_mfma_f32_16x16x32_bf16(af[0][0], bw0, a0, 0, 0, 0);
      a0 = __builtin_amdgcn_mfma_f32_16x16x32_bf16(af[0][1], bw1, a0, 0, 0, 0);
      a0 = __builtin_amdgcn_mfma_f32_16x16x32_bf16(af[0][2], bw2, a0, 0, 0, 0);
      a1 = __builtin_amdgcn_mfma_f32_16x16x32_bf16(af[1][0], bw0, a1, 0, 0, 0);
      a1 = __builtin_amdgcn_mfma_f32_16x16x32_bf16(af[1][1], bw1, a1, 0, 0, 0);
      a1 = __builtin_amdgcn_mfma_f32_16x16x32_bf16(af[1][2], bw2, a1, 0, 0, 0);
      const float bias = b1[ng * 16 + r16];
#pragma unroll
      for (int r = 0; r < 4; ++r) {
        Hs[((2 * w + 0) * 16 + g4 * 4 + r) * LDH + ng * 16 + r16] = f2bf(fmaxf(a0[r] + bias, 0.f));
        Hs[((2 * w + 1) * 16 + g4 * 4 + r) * LDH + ng * 16 + r16] = f2bf(fmaxf(a1[r] + bias, 0.f));
      }
    }
  }
  __syncthreads();
  {  // layer 2 + maxpool: wave w owns centroid w (rows 32w..32w+31)
    bfrag hf[2][4];
#pragma unroll
    for (int mg2 = 0; mg2 < 2; ++mg2)
#pragma unroll
      for (int ks = 0; ks < 4; ++ks)
        hf[mg2][ks] = *(const bfrag*)&Hs[((2 * w + mg2) * 16 + r16) * LDH + ks * 32 + g4 * 8];
    const int gout = ctr0 + w;
#pragma unroll
    for (int ng = 0; ng < 16; ++ng) {
      facc4 a0 = {0.f, 0.f, 0.f, 0.f}, a1 = {0.f, 0.f, 0.f, 0.f};
#pragma unroll
      for (int ks = 0; ks < 4; ++ks) {
        const bfrag bw = *(const bfrag*)&W2T[(ng * 16 + r16) * H1D + ks * 32 + g4 * 8];
        a0 = __builtin_amdgcn_mfma_f32_16x16x32_bf16(hf[0][ks], bw, a0, 0, 0, 0);
        a1 = __builtin_amdgcn_mfma_f32_16x16x32_bf16(hf[1][ks], bw, a1, 0, 0, 0);
      }
      // max over the centroid's 32 rows; bias+relu commute with max
      float m0 = fmaxf(fmaxf(a0[0], a0[1]), fmaxf(a0[2], a0[3]));
      float m1 = fmaxf(fmaxf(a1[0], a1[1]), fmaxf(a1[2], a1[3]));
      float mm = fmaxf(m0, m1);
      mm = fmaxf(mm, __shfl_xor(mm, 16));
      mm = fmaxf(mm, __shfl_xor(mm, 32));
      const float ov = fmaxf(mm + b2[ng * 16 + r16], 0.f);
      if (lane < 16) out[(size_t)gout * H2D + ng * 16 + lane] = ov;
    }
  }
}

extern "C" void kernel_launch(void* const* d_in, const int* in_sizes, int n_in,
                              void* d_out, int out_size, void* d_ws, size_t ws_size,
                              hipStream_t stream) {
  const float* x = (const float*)d_in[0];
  const float* pos = (const float*)d_in[1];
  const float* W1 = (const float*)d_in[2];
  const float* b1 = (const float*)d_in[3];
  const float* W2 = (const float*)d_in[4];
  const float* b2 = (const float*)d_in[5];
  float* out = (float*)d_out;
  char* ws = (char*)d_ws;
  u16* W1T = (u16*)(ws + 0);           // 24576 B
  u16* W2T = (u16*)(ws + 24576);       // 65536 B
  int* samp = (int*)(ws + 90112);      // 65536 B
  int* nbr = (int*)(ws + 155648);      // 2 MiB
  float* pos_s = out + OUTOFF;

  setup_kernel<<<dim3(176), dim3(256), 0, stream>>>(W1, W2, W1T, W2T);
  fps_kernel<<<dim3(NB), dim3(256), 0, stream>>>(pos, samp, pos_s);
  ballq_kernel<<<dim3(NB * NS / 4), dim3(256), 0, stream>>>(pos, samp, nbr);
  mlp_kernel<<<dim3(NB * NS / 4), dim3(256), 0, stream>>>(x, pos, b1, b2, nbr, W1T, W2T,
                                                          pos_s, out);
}